// Round 7
// baseline (214.412 us; speedup 1.0000x reference)
//
#include <hip/hip_runtime.h>

#define D 64          // node/edge feature dim
#define HID 128       // hidden dim
#define MLPB 1024     // MLP block size (16 waves)
#define WPB 16        // waves per MLP block
#define NB 8          // nodes per wave-batch
#define CAP 96        // elist slots per node (mean degree 32; Poisson tail ~0)
#define WIN_SHIFT 13  // 8192 nodes per place-window -> ~3MB elist window

typedef unsigned short ush;

// bf16 round-to-nearest-even (finite normals)
__device__ __forceinline__ ush f2bf(float f)
{
    unsigned u = __float_as_uint(f);
    return (ush)((u + 0x7FFF + ((u >> 16) & 1)) >> 16);
}
__device__ __forceinline__ float bf_lo(unsigned p) { return __uint_as_float(p << 16); }
__device__ __forceinline__ float bf_hi(unsigned p) { return __uint_as_float(p & 0xFFFF0000u); }

// ---------------------------------------------------------------------------
// Index dtype: reference says int64, harness may deliver int32. Probe high
// words of the first 64 pairs: int64 -> all zero (ids < 50000); int32 ->
// random node ids, P(all zero) ~ (2e-5)^64 ~ 0. Deterministic.
// ---------------------------------------------------------------------------
__device__ __forceinline__ bool detect_i64(const int* __restrict__ eidx, int lane)
{
    int probe = eidx[2 * lane + 1];
    return (__ballot(probe == 0) == ~0ULL);
}

// ---------------------------------------------------------------------------
// Windowed fixed-capacity place. Entry t in [0,2E): t<E -> src of edge t,
// else dst of edge t-E. blockIdx.y = node window; only in-window entries are
// committed this pass, so the window's elist range (~3MB) and counts stay
// cache-resident and a node's consecutive slots coalesce on few lines.
// Overflow (c >= CAP) goes to a list handled by a cleanup kernel.
// ---------------------------------------------------------------------------
__global__ __launch_bounds__(256)
void p1_place(const int* __restrict__ eidx, int* __restrict__ counts,
              int* __restrict__ elist, int* __restrict__ ovf_cnt,
              int2* __restrict__ ovf, int n_edges, int n_nodes)
{
    const int lo = blockIdx.y << WIN_SHIFT;
    const int hi = lo + (1 << WIN_SHIFT);
    const int E2 = 2 * n_edges;
    const bool is64 = detect_i64(eidx, threadIdx.x & 63);
    const int stride = gridDim.x * 256;
    for (int t = blockIdx.x * 256 + threadIdx.x; t < E2; t += stride) {
        int idx = is64 ? eidx[2 * (size_t)t] : eidx[t];
        if (idx >= lo && idx < hi) {
            int eid = (t < n_edges) ? t : t - n_edges;
            int c = atomicAdd(&counts[idx], 1);
            if (c < CAP) elist[(size_t)idx * CAP + c] = eid;
            else {
                int p = atomicAdd(ovf_cnt, 1);
                ovf[p] = make_int2(idx, eid);
            }
        }
    }
}

// ---------------------------------------------------------------------------
// Gather: agg[n] = sum over incident edges of x_edge[e]. One wave per node.
// 16 lanes x float4 cover one 256B row; 4 row slots (lane>>4), 8x unrolled
// -> 32 edges (8 x 16B loads per lane) in flight. No LDS, full occupancy.
// Typical degree ~32 -> one main iteration covers the whole node.
// ---------------------------------------------------------------------------
__global__ __launch_bounds__(256)
void p2_gather(const float* __restrict__ x_edge, const int* __restrict__ counts,
               const int* __restrict__ elist, float* __restrict__ agg, int n_nodes)
{
    const int w = (blockIdx.x * 256 + threadIdx.x) >> 6;
    if (w >= n_nodes) return;
    const int lane = threadIdx.x & 63;
    const int sub = lane >> 4;       // row slot 0..3
    const int q   = lane & 15;       // float4 index within row
    const float4* __restrict__ xe4 = (const float4*)x_edge;

    int cnt = counts[w]; if (cnt > CAP) cnt = CAP;
    const int beg = w * CAP, end = beg + cnt;
    float4 acc = make_float4(0.f, 0.f, 0.f, 0.f);

    int i = beg + sub;
    for (; i + 28 < end; i += 32) {
        int e0 = elist[i];      int e1 = elist[i + 4];
        int e2 = elist[i + 8];  int e3 = elist[i + 12];
        int e4 = elist[i + 16]; int e5 = elist[i + 20];
        int e6 = elist[i + 24]; int e7 = elist[i + 28];
        float4 v0 = xe4[(size_t)e0 * 16 + q];
        float4 v1 = xe4[(size_t)e1 * 16 + q];
        float4 v2 = xe4[(size_t)e2 * 16 + q];
        float4 v3 = xe4[(size_t)e3 * 16 + q];
        float4 v4 = xe4[(size_t)e4 * 16 + q];
        float4 v5 = xe4[(size_t)e5 * 16 + q];
        float4 v6 = xe4[(size_t)e6 * 16 + q];
        float4 v7 = xe4[(size_t)e7 * 16 + q];
        acc.x += ((v0.x + v1.x) + (v2.x + v3.x)) + ((v4.x + v5.x) + (v6.x + v7.x));
        acc.y += ((v0.y + v1.y) + (v2.y + v3.y)) + ((v4.y + v5.y) + (v6.y + v7.y));
        acc.z += ((v0.z + v1.z) + (v2.z + v3.z)) + ((v4.z + v5.z) + (v6.z + v7.z));
        acc.w += ((v0.w + v1.w) + (v2.w + v3.w)) + ((v4.w + v5.w) + (v6.w + v7.w));
    }
    for (; i < end; i += 4) {
        float4 v = xe4[(size_t)elist[i] * 16 + q];
        acc.x += v.x; acc.y += v.y; acc.z += v.z; acc.w += v.w;
    }

    // reduce across the 4 row slots (lane bits 4,5)
    #pragma unroll
    for (int m = 16; m < 64; m <<= 1) {
        acc.x += __shfl_xor(acc.x, m);
        acc.y += __shfl_xor(acc.y, m);
        acc.z += __shfl_xor(acc.z, m);
        acc.w += __shfl_xor(acc.w, m);
    }
    if (sub == 0)
        ((float4*)agg)[(size_t)w * 16 + q] = acc;
}

// ---------------------------------------------------------------------------
// Overflow cleanup: usually 0 entries. One wave per entry, atomic add of the
// edge row into agg. Runs after p2_gather (which overwrites agg rows).
// ---------------------------------------------------------------------------
__global__ __launch_bounds__(256)
void p3_ovf(const float* __restrict__ x_edge, const int* __restrict__ ovf_cnt,
            const int2* __restrict__ ovf, float* __restrict__ agg)
{
    const int n = *ovf_cnt;
    const int lane = threadIdx.x & 63;
    const int wv = (blockIdx.x * 256 + threadIdx.x) >> 6;
    const int nw = gridDim.x * 4;
    for (int i = wv; i < n; i += nw) {
        int2 p = ovf[i];
        float v = x_edge[(size_t)p.y * D + lane];
        unsafeAtomicAdd(&agg[(size_t)p.x * D + lane], v);
    }
}

// ---------- fallback atomic scatter (tiny ws) ------------------------------
__global__ __launch_bounds__(256)
void nb_scatter(const float* __restrict__ x_edge, const int* __restrict__ eidx,
                float* __restrict__ agg, int n_edges)
{
    long long t = (long long)blockIdx.x * 256 + threadIdx.x;
    int e = (int)(t >> 6);
    if (e >= n_edges) return;
    int d = (int)(t & 63);
    bool is64 = detect_i64(eidx, threadIdx.x & 63);
    int s, dd;
    if (is64) {
        s  = eidx[2 * (size_t)e];
        dd = eidx[2 * ((size_t)n_edges + (size_t)e)];
    } else {
        s  = eidx[e];
        dd = eidx[n_edges + e];
    }
    float v = x_edge[(size_t)e * D + d];
    unsafeAtomicAdd(&agg[(size_t)s * D + d], v);
    unsafeAtomicAdd(&agg[(size_t)dd * D + d], v);
}

// ---------------------------------------------------------------------------
// MLP: out[n] = relu(concat(x_node[n], agg[n]) @ W1 + b1) @ W2 + b2
// NB=8 nodes per wave-batch. W1 staged as float2{W1[k][j],W1[k][j+64]} (one
// b64 feeds 16 FMAs); W2 staged bf16-packed (one b32 feeds 32 FMAs). s_buf
// holds inputs then hidden (overlaid). LDS ~145KB -> 1 block/CU, 16 waves.
// agg read from d_out, out written in place (row n touched only by its wave).
// ---------------------------------------------------------------------------
__global__ __launch_bounds__(MLPB, 1)
void p4_mlp(const float* __restrict__ x_node, const float* __restrict__ agg,
            const float* __restrict__ W1, const float* __restrict__ b1,
            const float* __restrict__ W2, const float* __restrict__ b2,
            float* __restrict__ out, int n_nodes)
{
    __shared__ float2   sW1p[HID * 64];        // 64 KB
    __shared__ unsigned sW2p[64 * 64];         // 16 KB
    __shared__ float    sb1[HID];
    __shared__ float    sb2[D];
    __shared__ float4   s_buf[WPB][128][2];    // 64 KB

    {
        for (int t = threadIdx.x; t < HID * 64; t += MLPB) {
            int k = t >> 6, j = t & 63;
            sW1p[t] = make_float2(W1[k * HID + j], W1[k * HID + 64 + j]);
        }
        for (int t = threadIdx.x; t < 64 * 64; t += MLPB) {
            int q = t >> 6, j = t & 63;
            unsigned lo = f2bf(W2[(2 * q) * D + j]);
            unsigned hi = f2bf(W2[(2 * q + 1) * D + j]);
            sW2p[t] = lo | (hi << 16);
        }
        if (threadIdx.x < 128) sb1[threadIdx.x] = b1[threadIdx.x];
        else if (threadIdx.x < 192) sb2[threadIdx.x - 128] = b2[threadIdx.x - 128];
    }
    __syncthreads();

    const int wave = threadIdx.x >> 6;
    const int lane = threadIdx.x & 63;
    const int group = blockIdx.x * WPB + wave;
    const int ngroups = gridDim.x * WPB;
    const int nbatches = (n_nodes + NB - 1) / NB;

    const float bh0 = sb1[lane], bh1 = sb1[64 + lane];
    const float bo  = sb2[lane];

    for (int g = group; g < nbatches; g += ngroups) {
        const int n0 = g * NB;

        float vx[NB], va[NB];
        #pragma unroll
        for (int b = 0; b < NB; ++b) {
            const int n = n0 + b;
            const bool ok = (n < n_nodes);
            vx[b] = ok ? x_node[(size_t)n * D + lane] : 0.f;
            va[b] = ok ? agg[(size_t)n * D + lane] : 0.f;
        }
        s_buf[wave][lane][0]      = make_float4(vx[0], vx[1], vx[2], vx[3]);
        s_buf[wave][lane][1]      = make_float4(vx[4], vx[5], vx[6], vx[7]);
        s_buf[wave][64 + lane][0] = make_float4(va[0], va[1], va[2], va[3]);
        s_buf[wave][64 + lane][1] = make_float4(va[4], va[5], va[6], va[7]);
        __builtin_amdgcn_wave_barrier();

        float a0[NB], a1[NB];
        #pragma unroll
        for (int b = 0; b < NB; ++b) { a0[b] = bh0; a1[b] = bh1; }

        #pragma unroll 2
        for (int k = 0; k < 128; ++k) {
            const float4 A0 = s_buf[wave][k][0];
            const float4 A1 = s_buf[wave][k][1];
            const float2 w  = sW1p[k * 64 + lane];
            a0[0] = fmaf(A0.x, w.x, a0[0]); a1[0] = fmaf(A0.x, w.y, a1[0]);
            a0[1] = fmaf(A0.y, w.x, a0[1]); a1[1] = fmaf(A0.y, w.y, a1[1]);
            a0[2] = fmaf(A0.z, w.x, a0[2]); a1[2] = fmaf(A0.z, w.y, a1[2]);
            a0[3] = fmaf(A0.w, w.x, a0[3]); a1[3] = fmaf(A0.w, w.y, a1[3]);
            a0[4] = fmaf(A1.x, w.x, a0[4]); a1[4] = fmaf(A1.x, w.y, a1[4]);
            a0[5] = fmaf(A1.y, w.x, a0[5]); a1[5] = fmaf(A1.y, w.y, a1[5]);
            a0[6] = fmaf(A1.z, w.x, a0[6]); a1[6] = fmaf(A1.z, w.y, a1[6]);
            a0[7] = fmaf(A1.w, w.x, a0[7]); a1[7] = fmaf(A1.w, w.y, a1[7]);
        }
        __builtin_amdgcn_wave_barrier();
        s_buf[wave][lane][0] = make_float4(fmaxf(a0[0], 0.f), fmaxf(a0[1], 0.f),
                                           fmaxf(a0[2], 0.f), fmaxf(a0[3], 0.f));
        s_buf[wave][lane][1] = make_float4(fmaxf(a0[4], 0.f), fmaxf(a0[5], 0.f),
                                           fmaxf(a0[6], 0.f), fmaxf(a0[7], 0.f));
        s_buf[wave][64 + lane][0] = make_float4(fmaxf(a1[0], 0.f), fmaxf(a1[1], 0.f),
                                                fmaxf(a1[2], 0.f), fmaxf(a1[3], 0.f));
        s_buf[wave][64 + lane][1] = make_float4(fmaxf(a1[4], 0.f), fmaxf(a1[5], 0.f),
                                                fmaxf(a1[6], 0.f), fmaxf(a1[7], 0.f));
        __builtin_amdgcn_wave_barrier();

        float o[NB];
        #pragma unroll
        for (int b = 0; b < NB; ++b) o[b] = bo;
        #pragma unroll 2
        for (int q2 = 0; q2 < 64; ++q2) {
            const unsigned wp = sW2p[q2 * 64 + lane];
            const float w0 = bf_lo(wp), w1 = bf_hi(wp);
            const float4 H0a = s_buf[wave][2 * q2][0];
            const float4 H0b = s_buf[wave][2 * q2][1];
            const float4 H1a = s_buf[wave][2 * q2 + 1][0];
            const float4 H1b = s_buf[wave][2 * q2 + 1][1];
            o[0] = fmaf(H0a.x, w0, o[0]); o[0] = fmaf(H1a.x, w1, o[0]);
            o[1] = fmaf(H0a.y, w0, o[1]); o[1] = fmaf(H1a.y, w1, o[1]);
            o[2] = fmaf(H0a.z, w0, o[2]); o[2] = fmaf(H1a.z, w1, o[2]);
            o[3] = fmaf(H0a.w, w0, o[3]); o[3] = fmaf(H1a.w, w1, o[3]);
            o[4] = fmaf(H0b.x, w0, o[4]); o[4] = fmaf(H1b.x, w1, o[4]);
            o[5] = fmaf(H0b.y, w0, o[5]); o[5] = fmaf(H1b.y, w1, o[5]);
            o[6] = fmaf(H0b.z, w0, o[6]); o[6] = fmaf(H1b.z, w1, o[6]);
            o[7] = fmaf(H0b.w, w0, o[7]); o[7] = fmaf(H1b.w, w1, o[7]);
        }
        #pragma unroll
        for (int b = 0; b < NB; ++b) {
            const int n = n0 + b;
            if (n < n_nodes) out[(size_t)n * D + lane] = o[b];
        }
    }
}

// ---------------------------------------------------------------------------
extern "C" void kernel_launch(void* const* d_in, const int* in_sizes, int n_in,
                              void* d_out, int out_size, void* d_ws, size_t ws_size,
                              hipStream_t stream)
{
    const float* x_node = (const float*)d_in[0];
    const float* x_edge = (const float*)d_in[1];
    const int*   eidx   = (const int*)d_in[2];
    const float* W1     = (const float*)d_in[3];
    const float* b1     = (const float*)d_in[4];
    const float* W2     = (const float*)d_in[5];
    const float* b2     = (const float*)d_in[6];
    float* out = (float*)d_out;

    const int n_nodes = in_sizes[0] / D;     // 50000
    const int n_edges = in_sizes[2] / 2;     // 800000
    const int E2 = 2 * n_edges;

    float* agg = out;   // agg lives in d_out; MLP rewrites rows in place

    // ws layout (ints): counts[N] | ovf_cnt[1] | pad | ovf[2E int2] | elist[N*CAP]
    const size_t w_counts = (size_t)n_nodes;
    const size_t w_ovfc   = w_counts + 1;
    const size_t w_ovf    = (w_ovfc + 1 + 1) & ~(size_t)1;       // 8B align
    const size_t w_elist  = w_ovf + (size_t)E2 * 2;
    const size_t w_total  = w_elist + (size_t)n_nodes * CAP;
    const size_t need     = w_total * 4;

    if (ws_size >= need) {
        int*  counts  = (int*)d_ws;
        int*  ovf_cnt = (int*)d_ws + w_ovfc;
        int2* ovf     = (int2*)((int*)d_ws + w_ovf);
        int*  elist   = (int*)d_ws + w_elist;

        // zero counts + ovf_cnt (contiguous region)
        hipMemsetAsync(counts, 0, ((size_t)n_nodes + 2) * 4, stream);

        const int n_windows = (n_nodes + (1 << WIN_SHIFT) - 1) >> WIN_SHIFT;  // 7
        p1_place<<<dim3(1024, n_windows), 256, 0, stream>>>(
            eidx, counts, elist, ovf_cnt, ovf, n_edges, n_nodes);

        p2_gather<<<(n_nodes * 64 + 255) / 256, 256, 0, stream>>>(
            x_edge, counts, elist, agg, n_nodes);

        p3_ovf<<<64, 256, 0, stream>>>(x_edge, ovf_cnt, ovf, agg);
    } else {
        hipMemsetAsync(agg, 0, (size_t)n_nodes * D * sizeof(float), stream);
        long long threads = (long long)n_edges * 64;
        nb_scatter<<<(int)((threads + 255) / 256), 256, 0, stream>>>(
            x_edge, eidx, agg, n_edges);
    }

    p4_mlp<<<256, MLPB, 0, stream>>>(x_node, agg, W1, b1, W2, b2, out, n_nodes);
}

// Round 8
// 199.838 us; speedup vs baseline: 1.0729x; 1.0729x over previous
//
#include <hip/hip_runtime.h>

#define D 64          // node/edge feature dim
#define HID 128       // hidden dim
#define MLPB 1024     // MLP block size (16 waves)
#define WPB 16        // waves per MLP block
#define NB 8          // nodes per wave-batch
#define CAP 96        // elist slots per node (mean degree 32; Poisson tail ~0)
#define WIN_SHIFT 12  // 4096 nodes per place-window -> ~1.5MB elist window (R6-proven)

typedef unsigned short ush;

// bf16 round-to-nearest-even (finite normals)
__device__ __forceinline__ ush f2bf(float f)
{
    unsigned u = __float_as_uint(f);
    return (ush)((u + 0x7FFF + ((u >> 16) & 1)) >> 16);
}
__device__ __forceinline__ float bf_lo(unsigned p) { return __uint_as_float(p << 16); }
__device__ __forceinline__ float bf_hi(unsigned p) { return __uint_as_float(p & 0xFFFF0000u); }

// ---------------------------------------------------------------------------
// Index dtype: reference says int64, harness may deliver int32. Probe high
// words of the first 64 pairs: int64 -> all zero (ids < 50000); int32 ->
// random node ids, P(all zero) ~ (2e-5)^64 ~ 0. Deterministic.
// ---------------------------------------------------------------------------
__device__ __forceinline__ bool detect_i64(const int* __restrict__ eidx, int lane)
{
    int probe = eidx[2 * lane + 1];
    return (__ballot(probe == 0) == ~0ULL);
}

// ---------------------------------------------------------------------------
// p0: decode edge_index once into u16 node ids (3.2MB, cache-resident for the
// place sweeps) and zero counts+ovf_cnt (folds the memset launch away).
// Entry t in [0,2E): t<E -> src of edge t; t>=E -> dst of edge t-E.
// ---------------------------------------------------------------------------
__global__ __launch_bounds__(256)
void p0_nid(const int* __restrict__ eidx, ush* __restrict__ nid,
            int* __restrict__ counts, int n_zero, int n_edges)
{
    const int t = blockIdx.x * 256 + threadIdx.x;
    const bool is64 = detect_i64(eidx, threadIdx.x & 63);
    const int E2 = 2 * n_edges;
    if (t < E2) nid[t] = (ush)(is64 ? eidx[2 * (size_t)t] : eidx[t]);
    if (t < n_zero) counts[t] = 0;
}

// ---------------------------------------------------------------------------
// Windowed fixed-capacity place (u16 nid input). blockIdx.y = node window;
// only in-window entries are committed this pass, so the window's elist range
// (~1.5MB) and counts stay cache-resident and a node's consecutive slots
// coalesce on few lines. Overflow (c >= CAP) goes to a cleanup list.
// ---------------------------------------------------------------------------
__global__ __launch_bounds__(256)
void p1_place16(const ush* __restrict__ nid, int* __restrict__ counts,
                int* __restrict__ elist, int* __restrict__ ovf_cnt,
                int2* __restrict__ ovf, int n_edges)
{
    const int lo = blockIdx.y << WIN_SHIFT;
    const int hi = lo + (1 << WIN_SHIFT);
    const int E2 = 2 * n_edges;
    const int stride = gridDim.x * 256;
    for (int t = blockIdx.x * 256 + threadIdx.x; t < E2; t += stride) {
        int idx = nid[t];
        if (idx >= lo && idx < hi) {
            int eid = (t < n_edges) ? t : t - n_edges;
            int c = atomicAdd(&counts[idx], 1);
            if (c < CAP) elist[(size_t)idx * CAP + c] = eid;
            else {
                int p = atomicAdd(ovf_cnt, 1);
                ovf[p] = make_int2(idx, eid);
            }
        }
    }
}

// int fallback (n_nodes > 65535): identical logic, decodes eidx per pass.
__global__ __launch_bounds__(256)
void p1_place(const int* __restrict__ eidx, int* __restrict__ counts,
              int* __restrict__ elist, int* __restrict__ ovf_cnt,
              int2* __restrict__ ovf, int n_edges)
{
    const int lo = blockIdx.y << WIN_SHIFT;
    const int hi = lo + (1 << WIN_SHIFT);
    const int E2 = 2 * n_edges;
    const bool is64 = detect_i64(eidx, threadIdx.x & 63);
    const int stride = gridDim.x * 256;
    for (int t = blockIdx.x * 256 + threadIdx.x; t < E2; t += stride) {
        int idx = is64 ? eidx[2 * (size_t)t] : eidx[t];
        if (idx >= lo && idx < hi) {
            int eid = (t < n_edges) ? t : t - n_edges;
            int c = atomicAdd(&counts[idx], 1);
            if (c < CAP) elist[(size_t)idx * CAP + c] = eid;
            else {
                int p = atomicAdd(ovf_cnt, 1);
                ovf[p] = make_int2(idx, eid);
            }
        }
    }
}

// ---------------------------------------------------------------------------
// Gather: agg[n] = sum over incident edges of x_edge[e]. One wave per node.
// 16 lanes x float4 cover one 256B row; 4 row slots (lane>>4), 4x unrolled
// -> 16 edges in flight (R6-proven depth). No LDS, full occupancy.
// ---------------------------------------------------------------------------
__global__ __launch_bounds__(256)
void p2_gather(const float* __restrict__ x_edge, const int* __restrict__ counts,
               const int* __restrict__ elist, float* __restrict__ agg, int n_nodes)
{
    const int w = (blockIdx.x * 256 + threadIdx.x) >> 6;
    if (w >= n_nodes) return;
    const int lane = threadIdx.x & 63;
    const int sub = lane >> 4;       // row slot 0..3
    const int q   = lane & 15;       // float4 index within row
    const float4* __restrict__ xe4 = (const float4*)x_edge;

    int cnt = counts[w]; if (cnt > CAP) cnt = CAP;
    const int beg = w * CAP, end = beg + cnt;
    float4 acc = make_float4(0.f, 0.f, 0.f, 0.f);

    int i = beg + sub;
    for (; i + 12 < end; i += 16) {
        int e0 = elist[i];
        int e1 = elist[i + 4];
        int e2 = elist[i + 8];
        int e3 = elist[i + 12];
        float4 v0 = xe4[(size_t)e0 * 16 + q];
        float4 v1 = xe4[(size_t)e1 * 16 + q];
        float4 v2 = xe4[(size_t)e2 * 16 + q];
        float4 v3 = xe4[(size_t)e3 * 16 + q];
        acc.x += (v0.x + v1.x) + (v2.x + v3.x);
        acc.y += (v0.y + v1.y) + (v2.y + v3.y);
        acc.z += (v0.z + v1.z) + (v2.z + v3.z);
        acc.w += (v0.w + v1.w) + (v2.w + v3.w);
    }
    for (; i < end; i += 4) {
        float4 v = xe4[(size_t)elist[i] * 16 + q];
        acc.x += v.x; acc.y += v.y; acc.z += v.z; acc.w += v.w;
    }

    // reduce across the 4 row slots (lane bits 4,5)
    #pragma unroll
    for (int m = 16; m < 64; m <<= 1) {
        acc.x += __shfl_xor(acc.x, m);
        acc.y += __shfl_xor(acc.y, m);
        acc.z += __shfl_xor(acc.z, m);
        acc.w += __shfl_xor(acc.w, m);
    }
    if (sub == 0)
        ((float4*)agg)[(size_t)w * 16 + q] = acc;
}

// ---------------------------------------------------------------------------
// Overflow cleanup: usually 0 entries. One wave per entry, atomic add of the
// edge row into agg. Runs after p2_gather (which overwrites agg rows).
// ---------------------------------------------------------------------------
__global__ __launch_bounds__(256)
void p3_ovf(const float* __restrict__ x_edge, const int* __restrict__ ovf_cnt,
            const int2* __restrict__ ovf, float* __restrict__ agg)
{
    const int n = *ovf_cnt;
    const int lane = threadIdx.x & 63;
    const int wv = (blockIdx.x * 256 + threadIdx.x) >> 6;
    const int nw = gridDim.x * 4;
    for (int i = wv; i < n; i += nw) {
        int2 p = ovf[i];
        float v = x_edge[(size_t)p.y * D + lane];
        unsafeAtomicAdd(&agg[(size_t)p.x * D + lane], v);
    }
}

// ---------- fallback atomic scatter (tiny ws) ------------------------------
__global__ __launch_bounds__(256)
void nb_scatter(const float* __restrict__ x_edge, const int* __restrict__ eidx,
                float* __restrict__ agg, int n_edges)
{
    long long t = (long long)blockIdx.x * 256 + threadIdx.x;
    int e = (int)(t >> 6);
    if (e >= n_edges) return;
    int d = (int)(t & 63);
    bool is64 = detect_i64(eidx, threadIdx.x & 63);
    int s, dd;
    if (is64) {
        s  = eidx[2 * (size_t)e];
        dd = eidx[2 * ((size_t)n_edges + (size_t)e)];
    } else {
        s  = eidx[e];
        dd = eidx[n_edges + e];
    }
    float v = x_edge[(size_t)e * D + d];
    unsafeAtomicAdd(&agg[(size_t)s * D + d], v);
    unsafeAtomicAdd(&agg[(size_t)dd * D + d], v);
}

// ---------------------------------------------------------------------------
// MLP: out[n] = relu(concat(x_node[n], agg[n]) @ W1 + b1) @ W2 + b2
// NB=8 nodes per wave-batch. W1 staged as float2{W1[k][j],W1[k][j+64]} (one
// b64 feeds 16 FMAs); W2 staged bf16-packed (one b32 feeds 32 FMAs). s_buf
// holds inputs then hidden (overlaid). LDS ~145KB -> 1 block/CU, 16 waves.
// agg read from d_out, out written in place (row n touched only by its wave).
// ---------------------------------------------------------------------------
__global__ __launch_bounds__(MLPB, 1)
void p4_mlp(const float* __restrict__ x_node, const float* __restrict__ agg,
            const float* __restrict__ W1, const float* __restrict__ b1,
            const float* __restrict__ W2, const float* __restrict__ b2,
            float* __restrict__ out, int n_nodes)
{
    __shared__ float2   sW1p[HID * 64];        // 64 KB
    __shared__ unsigned sW2p[64 * 64];         // 16 KB
    __shared__ float    sb1[HID];
    __shared__ float    sb2[D];
    __shared__ float4   s_buf[WPB][128][2];    // 64 KB

    {
        for (int t = threadIdx.x; t < HID * 64; t += MLPB) {
            int k = t >> 6, j = t & 63;
            sW1p[t] = make_float2(W1[k * HID + j], W1[k * HID + 64 + j]);
        }
        for (int t = threadIdx.x; t < 64 * 64; t += MLPB) {
            int q = t >> 6, j = t & 63;
            unsigned lo = f2bf(W2[(2 * q) * D + j]);
            unsigned hi = f2bf(W2[(2 * q + 1) * D + j]);
            sW2p[t] = lo | (hi << 16);
        }
        if (threadIdx.x < 128) sb1[threadIdx.x] = b1[threadIdx.x];
        else if (threadIdx.x < 192) sb2[threadIdx.x - 128] = b2[threadIdx.x - 128];
    }
    __syncthreads();

    const int wave = threadIdx.x >> 6;
    const int lane = threadIdx.x & 63;
    const int group = blockIdx.x * WPB + wave;
    const int ngroups = gridDim.x * WPB;
    const int nbatches = (n_nodes + NB - 1) / NB;

    const float bh0 = sb1[lane], bh1 = sb1[64 + lane];
    const float bo  = sb2[lane];

    for (int g = group; g < nbatches; g += ngroups) {
        const int n0 = g * NB;

        float vx[NB], va[NB];
        #pragma unroll
        for (int b = 0; b < NB; ++b) {
            const int n = n0 + b;
            const bool ok = (n < n_nodes);
            vx[b] = ok ? x_node[(size_t)n * D + lane] : 0.f;
            va[b] = ok ? agg[(size_t)n * D + lane] : 0.f;
        }
        s_buf[wave][lane][0]      = make_float4(vx[0], vx[1], vx[2], vx[3]);
        s_buf[wave][lane][1]      = make_float4(vx[4], vx[5], vx[6], vx[7]);
        s_buf[wave][64 + lane][0] = make_float4(va[0], va[1], va[2], va[3]);
        s_buf[wave][64 + lane][1] = make_float4(va[4], va[5], va[6], va[7]);
        __builtin_amdgcn_wave_barrier();

        float a0[NB], a1[NB];
        #pragma unroll
        for (int b = 0; b < NB; ++b) { a0[b] = bh0; a1[b] = bh1; }

        #pragma unroll 2
        for (int k = 0; k < 128; ++k) {
            const float4 A0 = s_buf[wave][k][0];
            const float4 A1 = s_buf[wave][k][1];
            const float2 w  = sW1p[k * 64 + lane];
            a0[0] = fmaf(A0.x, w.x, a0[0]); a1[0] = fmaf(A0.x, w.y, a1[0]);
            a0[1] = fmaf(A0.y, w.x, a0[1]); a1[1] = fmaf(A0.y, w.y, a1[1]);
            a0[2] = fmaf(A0.z, w.x, a0[2]); a1[2] = fmaf(A0.z, w.y, a1[2]);
            a0[3] = fmaf(A0.w, w.x, a0[3]); a1[3] = fmaf(A0.w, w.y, a1[3]);
            a0[4] = fmaf(A1.x, w.x, a0[4]); a1[4] = fmaf(A1.x, w.y, a1[4]);
            a0[5] = fmaf(A1.y, w.x, a0[5]); a1[5] = fmaf(A1.y, w.y, a1[5]);
            a0[6] = fmaf(A1.z, w.x, a0[6]); a1[6] = fmaf(A1.z, w.y, a1[6]);
            a0[7] = fmaf(A1.w, w.x, a0[7]); a1[7] = fmaf(A1.w, w.y, a1[7]);
        }
        __builtin_amdgcn_wave_barrier();
        s_buf[wave][lane][0] = make_float4(fmaxf(a0[0], 0.f), fmaxf(a0[1], 0.f),
                                           fmaxf(a0[2], 0.f), fmaxf(a0[3], 0.f));
        s_buf[wave][lane][1] = make_float4(fmaxf(a0[4], 0.f), fmaxf(a0[5], 0.f),
                                           fmaxf(a0[6], 0.f), fmaxf(a0[7], 0.f));
        s_buf[wave][64 + lane][0] = make_float4(fmaxf(a1[0], 0.f), fmaxf(a1[1], 0.f),
                                                fmaxf(a1[2], 0.f), fmaxf(a1[3], 0.f));
        s_buf[wave][64 + lane][1] = make_float4(fmaxf(a1[4], 0.f), fmaxf(a1[5], 0.f),
                                                fmaxf(a1[6], 0.f), fmaxf(a1[7], 0.f));
        __builtin_amdgcn_wave_barrier();

        float o[NB];
        #pragma unroll
        for (int b = 0; b < NB; ++b) o[b] = bo;
        #pragma unroll 2
        for (int q2 = 0; q2 < 64; ++q2) {
            const unsigned wp = sW2p[q2 * 64 + lane];
            const float w0 = bf_lo(wp), w1 = bf_hi(wp);
            const float4 H0a = s_buf[wave][2 * q2][0];
            const float4 H0b = s_buf[wave][2 * q2][1];
            const float4 H1a = s_buf[wave][2 * q2 + 1][0];
            const float4 H1b = s_buf[wave][2 * q2 + 1][1];
            o[0] = fmaf(H0a.x, w0, o[0]); o[0] = fmaf(H1a.x, w1, o[0]);
            o[1] = fmaf(H0a.y, w0, o[1]); o[1] = fmaf(H1a.y, w1, o[1]);
            o[2] = fmaf(H0a.z, w0, o[2]); o[2] = fmaf(H1a.z, w1, o[2]);
            o[3] = fmaf(H0a.w, w0, o[3]); o[3] = fmaf(H1a.w, w1, o[3]);
            o[4] = fmaf(H0b.x, w0, o[4]); o[4] = fmaf(H1b.x, w1, o[4]);
            o[5] = fmaf(H0b.y, w0, o[5]); o[5] = fmaf(H1b.y, w1, o[5]);
            o[6] = fmaf(H0b.z, w0, o[6]); o[6] = fmaf(H1b.z, w1, o[6]);
            o[7] = fmaf(H0b.w, w0, o[7]); o[7] = fmaf(H1b.w, w1, o[7]);
        }
        #pragma unroll
        for (int b = 0; b < NB; ++b) {
            const int n = n0 + b;
            if (n < n_nodes) out[(size_t)n * D + lane] = o[b];
        }
    }
}

// ---------------------------------------------------------------------------
extern "C" void kernel_launch(void* const* d_in, const int* in_sizes, int n_in,
                              void* d_out, int out_size, void* d_ws, size_t ws_size,
                              hipStream_t stream)
{
    const float* x_node = (const float*)d_in[0];
    const float* x_edge = (const float*)d_in[1];
    const int*   eidx   = (const int*)d_in[2];
    const float* W1     = (const float*)d_in[3];
    const float* b1     = (const float*)d_in[4];
    const float* W2     = (const float*)d_in[5];
    const float* b2     = (const float*)d_in[6];
    float* out = (float*)d_out;

    const int n_nodes = in_sizes[0] / D;     // 50000
    const int n_edges = in_sizes[2] / 2;     // 800000
    const int E2 = 2 * n_edges;

    float* agg = out;   // agg lives in d_out; MLP rewrites rows in place

    // ws layout (4B words): counts[N] | ovf_cnt | pad | ovf[2E int2] |
    //                       elist[N*CAP] | nid_u16[2E] (E2/2 words)
    const size_t w_counts = (size_t)n_nodes;
    const size_t w_ovfc   = w_counts + 1;
    const size_t w_ovf    = (w_ovfc + 1 + 1) & ~(size_t)1;       // 8B align
    const size_t w_elist  = w_ovf + (size_t)E2 * 2;
    const size_t w_nid    = w_elist + (size_t)n_nodes * CAP;
    const size_t w_total  = w_nid + ((size_t)E2 + 1) / 2;
    const size_t need     = w_total * 4;
    const bool u16_ok     = (n_nodes <= 65535);

    if (ws_size >= need) {
        int*  counts  = (int*)d_ws;
        int*  ovf_cnt = (int*)d_ws + w_ovfc;
        int2* ovf     = (int2*)((int*)d_ws + w_ovf);
        int*  elist   = (int*)d_ws + w_elist;
        ush*  nid     = (ush*)((int*)d_ws + w_nid);

        const int n_windows = (n_nodes + (1 << WIN_SHIFT) - 1) >> WIN_SHIFT;  // 13

        if (u16_ok) {
            // decode nid (u16) + zero counts/ovf_cnt in one streaming kernel
            p0_nid<<<(E2 + 255) / 256, 256, 0, stream>>>(
                eidx, nid, counts, n_nodes + 2, n_edges);
            p1_place16<<<dim3(512, n_windows), 256, 0, stream>>>(
                nid, counts, elist, ovf_cnt, ovf, n_edges);
        } else {
            hipMemsetAsync(counts, 0, ((size_t)n_nodes + 2) * 4, stream);
            p1_place<<<dim3(512, n_windows), 256, 0, stream>>>(
                eidx, counts, elist, ovf_cnt, ovf, n_edges);
        }

        p2_gather<<<(n_nodes * 64 + 255) / 256, 256, 0, stream>>>(
            x_edge, counts, elist, agg, n_nodes);

        p3_ovf<<<64, 256, 0, stream>>>(x_edge, ovf_cnt, ovf, agg);
    } else {
        hipMemsetAsync(agg, 0, (size_t)n_nodes * D * sizeof(float), stream);
        long long threads = (long long)n_edges * 64;
        nb_scatter<<<(int)((threads + 255) / 256), 256, 0, stream>>>(
            x_edge, eidx, agg, n_edges);
    }

    p4_mlp<<<196, MLPB, 0, stream>>>(x_node, agg, W1, b1, W2, b2, out, n_nodes);
}